// Round 1
// baseline (153.602 us; speedup 1.0000x reference)
//
#include <hip/hip_runtime.h>
#include <math.h>

#define V 16
#define NC 10
#define NPX 1024
#define NPY 1024

static constexpr float TF = 1e-4f;
static constexpr float INV_TF = 1.0f / TF;

// ws float layout:
// [0:16) sp_clipped, [16:32) d, [32:48) 1-d,
// [48:304) Cl[V][V], [304:560) Cr[V][V], [560:720) cls[V][NC]
#define WS_SP 0
#define WS_D 16
#define WS_OD 32
#define WS_CL 48
#define WS_CR 304
#define WS_CLS 560

__global__ void setup_kernel(const float* __restrict__ split_points,
                             const float* __restrict__ dir_logits,
                             const float* __restrict__ class_logits,
                             const float* __restrict__ child_logits,
                             float* __restrict__ ws) {
    const int t = threadIdx.x;
    if (t < V) {
        // clipped split points + direction sigmoid (plain temperature)
        float s = fminf(fmaxf(split_points[t], 0.1f), 0.9f);
        ws[WS_SP + t] = s;
        float dd = 1.0f / (1.0f + expf(-dir_logits[t]));
        ws[WS_D + t] = dd;
        ws[WS_OD + t] = 1.0f - dd;
        // Cl row t: softmax(child_logits[t,0,:] / TF)
        float u[V]; float m = -INFINITY;
        #pragma unroll
        for (int c = 0; c < V; ++c) { u[c] = child_logits[t * 2 * V + c] * INV_TF; m = fmaxf(m, u[c]); }
        float sum = 0.0f;
        #pragma unroll
        for (int c = 0; c < V; ++c) { u[c] = expf(u[c] - m); sum += u[c]; }
        #pragma unroll
        for (int c = 0; c < V; ++c) ws[WS_CL + t * V + c] = u[c] / sum;
    } else if (t < 2 * V) {
        // Cr row n: softmax(child_logits[n,1,:] / TF)
        const int n = t - V;
        float u[V]; float m = -INFINITY;
        #pragma unroll
        for (int c = 0; c < V; ++c) { u[c] = child_logits[n * 2 * V + V + c] * INV_TF; m = fmaxf(m, u[c]); }
        float sum = 0.0f;
        #pragma unroll
        for (int c = 0; c < V; ++c) { u[c] = expf(u[c] - m); sum += u[c]; }
        #pragma unroll
        for (int c = 0; c < V; ++c) ws[WS_CR + n * V + c] = u[c] / sum;
    } else if (t < 3 * V) {
        // cls row n: softmax(class_logits[n,:] / TF)
        const int n = t - 2 * V;
        float u[NC]; float m = -INFINITY;
        #pragma unroll
        for (int c = 0; c < NC; ++c) { u[c] = class_logits[n * NC + c] * INV_TF; m = fmaxf(m, u[c]); }
        float sum = 0.0f;
        #pragma unroll
        for (int c = 0; c < NC; ++c) { u[c] = expf(u[c] - m); sum += u[c]; }
        #pragma unroll
        for (int c = 0; c < NC; ++c) ws[WS_CLS + n * NC + c] = u[c] / sum;
    }
}

__device__ __forceinline__ float fast_sigmoid(float z) {
    // 1/(1+exp(-z)); saturates to exactly 1.0 (exp underflow -> 0) and
    // exactly 0.0 (exp overflow -> inf, rcp(inf) = 0), matching the
    // reference's saturated values bit-exactly.
    return __builtin_amdgcn_rcpf(1.0f + __expf(-z));
}

__global__ __launch_bounds__(256) void fractal_kernel(
        const float* __restrict__ ws,
        const float* __restrict__ xs,
        const float* __restrict__ ys,
        const int* __restrict__ max_depth_p,
        float* __restrict__ out,
        int B) {
    const int lane = threadIdx.x & 63;
    const int wave = threadIdx.x >> 6;
    const int tile = blockIdx.x * 4 + wave;       // one wave = one 8x8 pixel tile
    if (tile >= (B >> 6)) return;
    const int tx = tile >> 7;                     // 1024/8 = 128 tiles per dim
    const int ty = tile & 127;
    const int ix = tx * 8 + (lane >> 3);
    const int iy = ty * 8 + (lane & 7);
    const int p = ix * NPY + iy;

    const float x = xs[p];
    const float y = ys[p];
    const int depth = *max_depth_p;

    float np[V];
    #pragma unroll
    for (int n = 0; n < V; ++n) np[n] = 0.0f;
    np[0] = 1.0f;
    float minx = 0.0f, maxx = 1.0f, miny = 0.0f, maxy = 1.0f;

    #pragma unroll 1
    for (int t = 0; t < depth; ++t) {
        const float rx = maxx - minx;
        const float ry = maxy - miny;
        float nxt[V];
        #pragma unroll
        for (int c = 0; c < V; ++c) nxt[c] = 0.0f;
        float sum_l = 0.0f, sum_r = 0.0f;
        float acc_lmaxx = 0.0f, acc_rminx = 0.0f;
        float acc_lmaxy = 0.0f, acc_rminy = 0.0f;

        #pragma unroll
        for (int n = 0; n < V; ++n) {
            // Wave-uniform skip: zero-prob nodes contribute exact zeros
            // everywhere (saturated sigmoids give exact 0/1; fl((1-d)+d)==1),
            // so skipping them is bit-identical to the dense computation.
            if (__any(np[n] != 0.0f)) {
                const float spn = ws[WS_SP + n];   // uniform -> s_load
                const float dn  = ws[WS_D + n];
                const float odn = ws[WS_OD + n];
                const float sx = fmaf(spn, rx, minx);
                const float sy = fmaf(spn, ry, miny);
                const float h = fast_sigmoid((sx - x) * INV_TF);
                const float v = fast_sigmoid((sy - y) * INV_TF);
                const float l = fmaf(dn, v, odn * h) * np[n];
                const float r = np[n] - l;
                sum_l += l;
                sum_r += r;
                acc_lmaxx = fmaf(fmaf(dn, maxx, odn * sx), l, acc_lmaxx);
                acc_rminx = fmaf(fmaf(dn, minx, odn * sx), r, acc_rminx);
                acc_lmaxy = fmaf(fmaf(odn, maxy, dn * sy), l, acc_lmaxy);
                acc_rminy = fmaf(fmaf(odn, miny, dn * sy), r, acc_rminy);
                #pragma unroll
                for (int c = 0; c < V; ++c) {
                    nxt[c] = fmaf(l, ws[WS_CL + n * V + c],
                             fmaf(r, ws[WS_CR + n * V + c], nxt[c]));
                }
            }
        }

        float wsum = fmaxf(sum_l + sum_r, 1e-10f);
        const float inv_w = __builtin_amdgcn_rcpf(wsum);
        float psum = 0.0f;
        #pragma unroll
        for (int c = 0; c < V; ++c) psum += nxt[c];
        const float inv_p = __builtin_amdgcn_rcpf(fmaxf(psum, 1e-10f));
        #pragma unroll
        for (int c = 0; c < V; ++c) np[c] = nxt[c] * inv_p;

        const float nminx = fmaf(minx, sum_l, acc_rminx) * inv_w;
        const float nmaxx = fmaf(maxx, sum_r, acc_lmaxx) * inv_w;
        const float nminy = fmaf(miny, sum_l, acc_rminy) * inv_w;
        const float nmaxy = fmaf(maxy, sum_r, acc_lmaxy) * inv_w;
        minx = nminx; maxx = nmaxx; miny = nminy; maxy = nmaxy;
    }

    // class_probs = np @ cls  [V x NC], cls rows via scalar loads
    float o[NC];
    #pragma unroll
    for (int c = 0; c < NC; ++c) o[c] = 0.0f;
    #pragma unroll
    for (int n = 0; n < V; ++n) {
        if (__any(np[n] != 0.0f)) {
            #pragma unroll
            for (int c = 0; c < NC; ++c) o[c] = fmaf(np[n], ws[WS_CLS + n * NC + c], o[c]);
        }
    }

    // out offset p*10 floats = p*40 bytes: 8B-aligned -> float2 stores
    float2* op = reinterpret_cast<float2*>(out + (size_t)p * NC);
    #pragma unroll
    for (int c = 0; c < NC / 2; ++c) op[c] = make_float2(o[2 * c], o[2 * c + 1]);
}

extern "C" void kernel_launch(void* const* d_in, const int* in_sizes, int n_in,
                              void* d_out, int out_size, void* d_ws, size_t ws_size,
                              hipStream_t stream) {
    const float* split_points = (const float*)d_in[0];
    const float* dir_logits   = (const float*)d_in[1];
    const float* class_logits = (const float*)d_in[2];
    const float* child_logits = (const float*)d_in[3];
    const float* xs           = (const float*)d_in[4];
    const float* ys           = (const float*)d_in[5];
    const int*   max_depth    = (const int*)d_in[6];
    float* out = (float*)d_out;
    float* ws  = (float*)d_ws;   // needs 720 floats = 2880 B

    hipLaunchKernelGGL(setup_kernel, dim3(1), dim3(64), 0, stream,
                       split_points, dir_logits, class_logits, child_logits, ws);

    const int B = in_sizes[4];                 // 1048576 points
    const int blocks = (B + 255) / 256;        // 4 waves/block, 1 tile/wave
    hipLaunchKernelGGL(fractal_kernel, dim3(blocks), dim3(256), 0, stream,
                       ws, xs, ys, max_depth, out, B);
}